// Round 1
// baseline (1642.385 us; speedup 1.0000x reference)
//
#include <hip/hip_runtime.h>
#include <math.h>

namespace {

constexpr int Bn  = 4;
constexpr int Sn  = 1024;
constexpr int Hn  = 1024;
constexpr int NHn = 16;
constexpr int HDn = 64;
constexpr int Mn  = Bn * Sn;  // 4096 rows

__device__ __forceinline__ float sigmoidf_(float x) {
  return 1.0f / (1.0f + __expf(-x));
}

// ---------------------------------------------------------------------------
// GEMM: C[M,1024] = A @ W^T (+ bias) with fused epilogues.
//   MODE 0 (plain): C = A@W^T + b
//   MODE 1 (vsig) : C = (A@W^T + b) * sigmoid(gsrc)         (V projection)
//   MODE 2 (gate) : C = gsrc * sigmoid(concat(A,A2)@W^T+b)  (K = 2048)
// Tile 128x128, K-chunk 16, 256 threads, 8x8 microtile (2 FLOP / LDS byte).
// ---------------------------------------------------------------------------
template <int MODE>
__global__ __launch_bounds__(256) void gemm_xwt(
    const float* __restrict__ A, const float* __restrict__ A2,
    const float* __restrict__ W, const float* __restrict__ bias,
    const float* __restrict__ gsrc, float* __restrict__ C, int K) {
  __shared__ float as[16][132];  // +4 pad: conflict-free, keeps 16B alignment
  __shared__ float bs[16][132];
  const int t  = threadIdx.x;
  const int tx = t & 15;
  const int ty = t >> 4;
  const int n0 = blockIdx.x * 128;
  const int m0 = blockIdx.y * 128;

  float acc[8][8];
#pragma unroll
  for (int i = 0; i < 8; ++i)
#pragma unroll
    for (int j = 0; j < 8; ++j) acc[i][j] = 0.0f;

  const int r0 = t >> 2;        // rows 0..63
  const int r1 = r0 + 64;       // rows 64..127
  const int kq = (t & 3) << 2;  // k sub-offset 0,4,8,12

  const int nchunks = K >> 4;
  for (int c = 0; c < nchunks; ++c) {
    const int k0 = c << 4;
    const float* Ae = A;
    int ka = k0;
    if (MODE == 2 && k0 >= 1024) { Ae = A2; ka = k0 - 1024; }
    const float4 va0 = *(const float4*)(Ae + (size_t)(m0 + r0) * 1024 + ka + kq);
    const float4 va1 = *(const float4*)(Ae + (size_t)(m0 + r1) * 1024 + ka + kq);
    const float4 vb0 = *(const float4*)(W + (size_t)(n0 + r0) * K + k0 + kq);
    const float4 vb1 = *(const float4*)(W + (size_t)(n0 + r1) * K + k0 + kq);
    __syncthreads();  // previous chunk's readers done before overwrite
    as[kq + 0][r0] = va0.x; as[kq + 1][r0] = va0.y; as[kq + 2][r0] = va0.z; as[kq + 3][r0] = va0.w;
    as[kq + 0][r1] = va1.x; as[kq + 1][r1] = va1.y; as[kq + 2][r1] = va1.z; as[kq + 3][r1] = va1.w;
    bs[kq + 0][r0] = vb0.x; bs[kq + 1][r0] = vb0.y; bs[kq + 2][r0] = vb0.z; bs[kq + 3][r0] = vb0.w;
    bs[kq + 0][r1] = vb1.x; bs[kq + 1][r1] = vb1.y; bs[kq + 2][r1] = vb1.z; bs[kq + 3][r1] = vb1.w;
    __syncthreads();
#pragma unroll
    for (int kk = 0; kk < 16; ++kk) {
      const float4 a0 = *(const float4*)&as[kk][ty * 8];
      const float4 a1 = *(const float4*)&as[kk][ty * 8 + 4];
      const float4 b0 = *(const float4*)&bs[kk][tx * 8];
      const float4 b1 = *(const float4*)&bs[kk][tx * 8 + 4];
      const float aa[8] = {a0.x, a0.y, a0.z, a0.w, a1.x, a1.y, a1.z, a1.w};
      const float bb[8] = {b0.x, b0.y, b0.z, b0.w, b1.x, b1.y, b1.z, b1.w};
#pragma unroll
      for (int i = 0; i < 8; ++i)
#pragma unroll
        for (int j = 0; j < 8; ++j) acc[i][j] = fmaf(aa[i], bb[j], acc[i][j]);
    }
  }

#pragma unroll
  for (int i = 0; i < 8; ++i) {
    const int m = m0 + ty * 8 + i;
#pragma unroll
    for (int j = 0; j < 8; ++j) {
      const int n = n0 + tx * 8 + j;
      const size_t idx = (size_t)m * 1024 + n;
      const float v = acc[i][j] + bias[n];
      if (MODE == 0) {
        C[idx] = v;
      } else if (MODE == 1) {
        C[idx] = v * sigmoidf_(gsrc[idx]);
      } else {
        C[idx] = gsrc[idx] * sigmoidf_(v);
      }
    }
  }
}

// ---------------------------------------------------------------------------
// Attention: one block per (b, h, 64-row Q tile); flash-style online softmax.
//   s_ij = (q.k * 0.125) * exp(-|i-j|/tau_h) * (1 + (sq.sk * 0.125))
//   v already gated by sigmoid(membrane) in the V projection.
// 256 threads, 4x4 microtile; 64-row K/V chunks. LDS ~102 KB -> 1 block/CU.
// ---------------------------------------------------------------------------
__global__ __launch_bounds__(256) void attn_kernel(
    const float* __restrict__ Q, const float* __restrict__ Km,
    const float* __restrict__ V, const float* __restrict__ spikes,
    const float* __restrict__ tau, float* __restrict__ CTX) {
  __shared__ float qT[64][68];   // qT[d][i]
  __shared__ float sqT[64][68];  // spike-q transposed
  __shared__ float kT[64][68];   // kT[d][j]
  __shared__ float skT[64][68];  // spike-k transposed
  __shared__ float vbuf[64][68]; // vbuf[j][d]
  __shared__ float pT[64][68];   // pT[j][i]

  const int t  = threadIdx.x;
  const int tx = t & 15;
  const int ty = t >> 4;
  const int qt = blockIdx.x;
  const int h  = blockIdx.y;
  const int b  = blockIdx.z;
  const int qi0 = qt * 64;
  const float inv_tau = 1.0f / tau[h];
  const float scale = 0.125f;  // 1/sqrt(64)

  const int li = t >> 2;        // staging row 0..63
  const int d0 = (t & 3) << 4;  // staging d offset 0,16,32,48

  {  // stage Q and spike-Q tiles (transposed)
    const size_t base = ((size_t)(b * Sn + qi0 + li)) * Hn + h * HDn + d0;
#pragma unroll
    for (int u = 0; u < 4; ++u) {
      const float4 qv = *(const float4*)(Q + base + u * 4);
      const float4 sv = *(const float4*)(spikes + base + u * 4);
      qT[d0 + u * 4 + 0][li] = qv.x; qT[d0 + u * 4 + 1][li] = qv.y;
      qT[d0 + u * 4 + 2][li] = qv.z; qT[d0 + u * 4 + 3][li] = qv.w;
      sqT[d0 + u * 4 + 0][li] = sv.x; sqT[d0 + u * 4 + 1][li] = sv.y;
      sqT[d0 + u * 4 + 2][li] = sv.z; sqT[d0 + u * 4 + 3][li] = sv.w;
    }
  }

  float m_old[4], lsum[4], ctx[4][4];
#pragma unroll
  for (int u = 0; u < 4; ++u) {
    m_old[u] = -INFINITY;
    lsum[u]  = 0.0f;
#pragma unroll
    for (int w = 0; w < 4; ++w) ctx[u][w] = 0.0f;
  }

  for (int jc = 0; jc < 16; ++jc) {
    const int j0 = jc * 64;
    const size_t base = ((size_t)(b * Sn + j0 + li)) * Hn + h * HDn + d0;
    float4 kr[4], sr[4], vr[4];
#pragma unroll
    for (int u = 0; u < 4; ++u) {
      kr[u] = *(const float4*)(Km + base + u * 4);
      sr[u] = *(const float4*)(spikes + base + u * 4);
      vr[u] = *(const float4*)(V + base + u * 4);
    }
    __syncthreads();  // everyone done with previous chunk's LDS
#pragma unroll
    for (int u = 0; u < 4; ++u) {
      kT[d0 + u * 4 + 0][li] = kr[u].x; kT[d0 + u * 4 + 1][li] = kr[u].y;
      kT[d0 + u * 4 + 2][li] = kr[u].z; kT[d0 + u * 4 + 3][li] = kr[u].w;
      skT[d0 + u * 4 + 0][li] = sr[u].x; skT[d0 + u * 4 + 1][li] = sr[u].y;
      skT[d0 + u * 4 + 2][li] = sr[u].z; skT[d0 + u * 4 + 3][li] = sr[u].w;
      *(float4*)&vbuf[li][d0 + u * 4] = vr[u];
    }
    __syncthreads();

    // ---- score phase: two 64-length dots per (i,j) -------------------------
    float qk[4][4], ss[4][4];
#pragma unroll
    for (int u = 0; u < 4; ++u)
#pragma unroll
      for (int w = 0; w < 4; ++w) { qk[u][w] = 0.0f; ss[u][w] = 0.0f; }
#pragma unroll 4
    for (int d = 0; d < 64; ++d) {
      const float4 qv  = *(const float4*)&qT[d][ty * 4];
      const float4 sqv = *(const float4*)&sqT[d][ty * 4];
      const float4 kv  = *(const float4*)&kT[d][tx * 4];
      const float4 skv = *(const float4*)&skT[d][tx * 4];
      const float qa[4]  = {qv.x, qv.y, qv.z, qv.w};
      const float sqa[4] = {sqv.x, sqv.y, sqv.z, sqv.w};
      const float ka[4]  = {kv.x, kv.y, kv.z, kv.w};
      const float ska[4] = {skv.x, skv.y, skv.z, skv.w};
#pragma unroll
      for (int u = 0; u < 4; ++u)
#pragma unroll
        for (int w = 0; w < 4; ++w) {
          qk[u][w] = fmaf(qa[u], ka[w], qk[u][w]);
          ss[u][w] = fmaf(sqa[u], ska[w], ss[u][w]);
        }
    }

    // ---- combine modifiers, online softmax update -------------------------
    float p[4][4], alpha[4];
#pragma unroll
    for (int u = 0; u < 4; ++u) {
      float rm = -INFINITY;
#pragma unroll
      for (int w = 0; w < 4; ++w) {
        const float di = fabsf((float)((qi0 + ty * 4 + u) - (j0 + tx * 4 + w)));
        const float sc = qk[u][w] * scale * __expf(-di * inv_tau) *
                         (1.0f + ss[u][w] * scale);
        p[u][w] = sc;
        rm = fmaxf(rm, sc);
      }
#pragma unroll
      for (int off = 1; off < 16; off <<= 1)
        rm = fmaxf(rm, __shfl_xor(rm, off, 16));
      const float mn = fmaxf(m_old[u], rm);
      alpha[u] = __expf(m_old[u] - mn);
      m_old[u] = mn;
      float rs = 0.0f;
#pragma unroll
      for (int w = 0; w < 4; ++w) {
        p[u][w] = __expf(p[u][w] - mn);
        rs += p[u][w];
      }
#pragma unroll
      for (int off = 1; off < 16; off <<= 1) rs += __shfl_xor(rs, off, 16);
      lsum[u] = lsum[u] * alpha[u] + rs;
    }
#pragma unroll
    for (int u = 0; u < 4; ++u)
#pragma unroll
      for (int w = 0; w < 4; ++w) pT[tx * 4 + w][ty * 4 + u] = p[u][w];
    __syncthreads();

    // ---- PV accumulate (thread: rows i=ty*4+u, cols d=tx*4+w) -------------
#pragma unroll
    for (int u = 0; u < 4; ++u)
#pragma unroll
      for (int w = 0; w < 4; ++w) ctx[u][w] *= alpha[u];
#pragma unroll 4
    for (int j2 = 0; j2 < 64; ++j2) {
      const float4 pv = *(const float4*)&pT[j2][ty * 4];
      const float4 vv = *(const float4*)&vbuf[j2][tx * 4];
      const float pa[4] = {pv.x, pv.y, pv.z, pv.w};
      const float va[4] = {vv.x, vv.y, vv.z, vv.w};
#pragma unroll
      for (int u = 0; u < 4; ++u)
#pragma unroll
        for (int w = 0; w < 4; ++w) ctx[u][w] = fmaf(pa[u], va[w], ctx[u][w]);
    }
  }

#pragma unroll
  for (int u = 0; u < 4; ++u) {
    const float inv_l = 1.0f / lsum[u];
    float4 o;
    o.x = ctx[u][0] * inv_l; o.y = ctx[u][1] * inv_l;
    o.z = ctx[u][2] * inv_l; o.w = ctx[u][3] * inv_l;
    *(float4*)(CTX + ((size_t)(b * Sn + qi0 + ty * 4 + u)) * Hn + h * HDn + tx * 4) = o;
  }
}

}  // namespace

extern "C" void kernel_launch(void* const* d_in, const int* in_sizes, int n_in,
                              void* d_out, int out_size, void* d_ws, size_t ws_size,
                              hipStream_t stream) {
  const float* x      = (const float*)d_in[0];
  const float* spikes = (const float*)d_in[1];
  const float* mem    = (const float*)d_in[2];
  const float* Wq     = (const float*)d_in[3];
  const float* bq     = (const float*)d_in[4];
  const float* Wk     = (const float*)d_in[5];
  const float* bk     = (const float*)d_in[6];
  const float* Wv     = (const float*)d_in[7];
  const float* bv     = (const float*)d_in[8];
  const float* Wo     = (const float*)d_in[9];
  const float* bo     = (const float*)d_in[10];
  const float* tau    = (const float*)d_in[11];
  const float* Wg     = (const float*)d_in[12];
  const float* bg     = (const float*)d_in[13];
  float* out = (float*)d_out;
  float* ws  = (float*)d_ws;

  const size_t NEL = (size_t)Mn * Hn;  // 4M floats
  float* Qb   = ws;            // 16 MB
  float* Kb   = ws + NEL;      // 16 MB
  float* Vb   = ws + 2 * NEL;  // 16 MB (gated V)
  float* CTX  = ws + 3 * NEL;  // 16 MB
  float* CTXG = Qb;            // alias: Q dead after attention

  const dim3 gg(8, 32), bb(256);
  // Q = x@Wq^T + bq ; K = x@Wk^T + bk ; Vg = (x@Wv^T + bv) * sigmoid(mem)
  gemm_xwt<0><<<gg, bb, 0, stream>>>(x, nullptr, Wq, bq, nullptr, Qb, 1024);
  gemm_xwt<0><<<gg, bb, 0, stream>>>(x, nullptr, Wk, bk, nullptr, Kb, 1024);
  gemm_xwt<1><<<gg, bb, 0, stream>>>(x, nullptr, Wv, bv, mem, Vb, 1024);
  // flash attention with temporal-decay * spike-correlation score modifiers
  attn_kernel<<<dim3(16, NHn, Bn), 256, 0, stream>>>(Qb, Kb, Vb, spikes, tau, CTX);
  // gated = ctx * sigmoid([ctx, mem] @ Wg^T + bg)
  gemm_xwt<2><<<gg, bb, 0, stream>>>(CTX, mem, Wg, bg, CTX, CTXG, 2048);
  // out = gated @ Wo^T + bo
  gemm_xwt<0><<<gg, bb, 0, stream>>>(CTXG, nullptr, Wo, bo, nullptr, out, 1024);
}

// Round 2
// 344.015 us; speedup vs baseline: 4.7742x; 4.7742x over previous
//
#include <hip/hip_runtime.h>
#include <math.h>
#include <stdint.h>

namespace {

typedef __attribute__((ext_vector_type(8))) short s8v;   // 8 bf16 = 4 VGPR (MFMA A/B)
typedef __attribute__((ext_vector_type(4))) float f4v;   // MFMA C/D
typedef unsigned short u16;

__device__ __forceinline__ u16 f2bf(float f) {  // RTN-even
  union { float f; uint32_t u; } v; v.f = f;
  uint32_t r = v.u + 0x7fffu + ((v.u >> 16) & 1u);
  return (u16)(r >> 16);
}
__device__ __forceinline__ float bf2f(u16 h) {
  union { uint32_t u; float f; } v; v.u = ((uint32_t)h) << 16;
  return v.f;
}
__device__ __forceinline__ float sigmoidf_(float x) { return 1.0f / (1.0f + __expf(-x)); }

// async global->LDS, 16B per lane. LDS dest must be wave-uniform base + lane*16.
__device__ __forceinline__ void gload16(const u16* g, u16* l) {
  __builtin_amdgcn_global_load_lds(
      (const __attribute__((address_space(1))) void*)g,
      (__attribute__((address_space(3))) void*)l, 16, 0, 0);
}

// ---------------------------------------------------------------------------
// bf16->  conversion (batched jobs)
// ---------------------------------------------------------------------------
struct CvtJob { const float* src; u16* dst; int n4; };
struct CvtArgs { CvtJob j[7]; };

__global__ __launch_bounds__(256) void cvt_kernel(CvtArgs a) {
  const CvtJob jb = a.j[blockIdx.y];
  const int i = blockIdx.x * 256 + threadIdx.x;
  if (i >= jb.n4) return;
  const float4 v = ((const float4*)jb.src)[i];
  uint2 pk;
  pk.x = (uint32_t)f2bf(v.x) | ((uint32_t)f2bf(v.y) << 16);
  pk.y = (uint32_t)f2bf(v.z) | ((uint32_t)f2bf(v.w) << 16);
  ((uint2*)jb.dst)[i] = pk;
}

// ---------------------------------------------------------------------------
// GEMM core: C[128,128] += A[M,K(bf16,pitch1024)] @ W[N,K(bf16,pitchK)]^T
// m97 structure: BK=32, global_load_lds w16, 4 waves each 64x64 (4x4 MFMA).
// ---------------------------------------------------------------------------
template <bool HASA2>
__device__ __forceinline__ void gemm_core(
    const u16* __restrict__ A, const u16* __restrict__ A2,
    const u16* __restrict__ W, int K, int m0, int n0,
    u16* as_, u16* bs_, f4v acc[4][4]) {
  const int t = threadIdx.x;
  const int l = t & 63;
  const int w = t >> 6, wm = w >> 1, wn = w & 1;
  const int lr = l & 15, lq = l >> 4;
  const int srow = t >> 2, sck = (t & 3) * 8;
  const int nc = K >> 5;
  for (int c = 0; c < nc; ++c) {
    const int k0 = c << 5;
    const u16* Ae = A;
    int ka = k0;
    if (HASA2) { if (k0 >= 1024) { Ae = A2; ka = k0 - 1024; } }
    __syncthreads();  // prior chunk's readers done
    gload16(Ae + (size_t)(m0 + srow) * 1024 + ka + sck, as_ + t * 8);
    gload16(Ae + (size_t)(m0 + 64 + srow) * 1024 + ka + sck, as_ + 2048 + t * 8);
    gload16(W + (size_t)(n0 + srow) * K + k0 + sck, bs_ + t * 8);
    gload16(W + (size_t)(n0 + 64 + srow) * K + k0 + sck, bs_ + 2048 + t * 8);
    __syncthreads();  // vmcnt(0) drained by barrier semantics
    s8v af[4], bf[4];
#pragma unroll
    for (int mi = 0; mi < 4; ++mi)
      af[mi] = *(const s8v*)(as_ + (wm * 64 + mi * 16 + lr) * 32 + lq * 8);
#pragma unroll
    for (int ni = 0; ni < 4; ++ni)
      bf[ni] = *(const s8v*)(bs_ + (wn * 64 + ni * 16 + lr) * 32 + lq * 8);
#pragma unroll
    for (int mi = 0; mi < 4; ++mi)
#pragma unroll
      for (int ni = 0; ni < 4; ++ni)
        acc[mi][ni] = __builtin_amdgcn_mfma_f32_16x16x32_bf16(af[mi], bf[ni], acc[mi][ni], 0, 0, 0);
  }
}

// ---------------------------------------------------------------------------
// Fused QKV projection. grid (24, 32): nb<8 -> Q, <16 -> K, else V (gated,
// stored transposed per-head: Vt[b][h][d][s]).
// ---------------------------------------------------------------------------
__global__ __launch_bounds__(256) void qkv_gemm(
    const u16* __restrict__ xb,
    const u16* __restrict__ Wqb, const u16* __restrict__ Wkb, const u16* __restrict__ Wvb,
    const float* __restrict__ bq, const float* __restrict__ bk, const float* __restrict__ bv,
    const float* __restrict__ mem,
    u16* __restrict__ Qb, u16* __restrict__ Kb, u16* __restrict__ Vt) {
  __shared__ u16 as_[4096], bs_[4096];
  const int nb = blockIdx.x, mb = blockIdx.y;
  const int sel = nb >> 3;
  const u16* W = sel == 0 ? Wqb : (sel == 1 ? Wkb : Wvb);
  const float* bias = sel == 0 ? bq : (sel == 1 ? bk : bv);
  const int m0 = mb * 128, n0 = (nb & 7) * 128;
  const f4v fz = {0.f, 0.f, 0.f, 0.f};
  f4v acc[4][4];
#pragma unroll
  for (int i = 0; i < 4; ++i)
#pragma unroll
    for (int j = 0; j < 4; ++j) acc[i][j] = fz;
  gemm_core<false>(xb, nullptr, W, 1024, m0, n0, as_, bs_, acc);

  const int t = threadIdx.x, l = t & 63, w = t >> 6, wm = w >> 1, wn = w & 1;
  const int lr = l & 15, lq = l >> 4;
  if (sel < 2) {
    u16* dst = (sel == 0) ? Qb : Kb;
#pragma unroll
    for (int mi = 0; mi < 4; ++mi)
#pragma unroll
      for (int ni = 0; ni < 4; ++ni) {
        const int mrow = m0 + wm * 64 + mi * 16 + lq * 4;
        const int ncol = n0 + wn * 64 + ni * 16 + lr;
        const float bi = bias[ncol];
#pragma unroll
        for (int r = 0; r < 4; ++r)
          dst[(size_t)(mrow + r) * 1024 + ncol] = f2bf(acc[mi][ni][r] + bi);
      }
  } else {
    const int b = m0 >> 10;  // block spans one batch row-range
#pragma unroll
    for (int mi = 0; mi < 4; ++mi)
#pragma unroll
      for (int ni = 0; ni < 4; ++ni) {
        const int mrow = m0 + wm * 64 + mi * 16 + lq * 4;
        const int ncol = n0 + wn * 64 + ni * 16 + lr;
        const int h = ncol >> 6, d = ncol & 63;
        const float bi = bias[ncol];
        u16 tmp[4];
#pragma unroll
        for (int r = 0; r < 4; ++r) {
          const float g = sigmoidf_(mem[(size_t)(mrow + r) * 1024 + ncol]);
          tmp[r] = f2bf((acc[mi][ni][r] + bi) * g);
        }
        const int s = mrow & 1023;
        uint2 pk;
        pk.x = (uint32_t)tmp[0] | ((uint32_t)tmp[1] << 16);
        pk.y = (uint32_t)tmp[2] | ((uint32_t)tmp[3] << 16);
        *(uint2*)(Vt + ((size_t)((b * 16 + h) * 64 + d)) * 1024 + s) = pk;
      }
  }
}

// gate = sigmoid([ctx, mem] @ Wg^T + bg); out = ctx * gate   (K = 2048)
__global__ __launch_bounds__(256) void gate_gemm(
    const u16* __restrict__ ctxb, const u16* __restrict__ memb,
    const u16* __restrict__ Wgb, const float* __restrict__ bg,
    u16* __restrict__ outg) {
  __shared__ u16 as_[4096], bs_[4096];
  const int m0 = blockIdx.y * 128, n0 = blockIdx.x * 128;
  const f4v fz = {0.f, 0.f, 0.f, 0.f};
  f4v acc[4][4];
#pragma unroll
  for (int i = 0; i < 4; ++i)
#pragma unroll
    for (int j = 0; j < 4; ++j) acc[i][j] = fz;
  gemm_core<true>(ctxb, memb, Wgb, 2048, m0, n0, as_, bs_, acc);
  const int t = threadIdx.x, l = t & 63, w = t >> 6, wm = w >> 1, wn = w & 1;
  const int lr = l & 15, lq = l >> 4;
#pragma unroll
  for (int mi = 0; mi < 4; ++mi)
#pragma unroll
    for (int ni = 0; ni < 4; ++ni) {
      const int mrow = m0 + wm * 64 + mi * 16 + lq * 4;
      const int ncol = n0 + wn * 64 + ni * 16 + lr;
      const float bi = bg[ncol];
#pragma unroll
      for (int r = 0; r < 4; ++r) {
        const size_t idx = (size_t)(mrow + r) * 1024 + ncol;
        outg[idx] = f2bf(bf2f(ctxb[idx]) * sigmoidf_(acc[mi][ni][r] + bi));
      }
    }
}

// out = gctx @ Wo^T + bo  (fp32 output)
__global__ __launch_bounds__(256) void out_gemm(
    const u16* __restrict__ gctx, const u16* __restrict__ Wob,
    const float* __restrict__ bo, float* __restrict__ out) {
  __shared__ u16 as_[4096], bs_[4096];
  const int m0 = blockIdx.y * 128, n0 = blockIdx.x * 128;
  const f4v fz = {0.f, 0.f, 0.f, 0.f};
  f4v acc[4][4];
#pragma unroll
  for (int i = 0; i < 4; ++i)
#pragma unroll
    for (int j = 0; j < 4; ++j) acc[i][j] = fz;
  gemm_core<false>(gctx, nullptr, Wob, 1024, m0, n0, as_, bs_, acc);
  const int t = threadIdx.x, l = t & 63, w = t >> 6, wm = w >> 1, wn = w & 1;
  const int lr = l & 15, lq = l >> 4;
#pragma unroll
  for (int mi = 0; mi < 4; ++mi)
#pragma unroll
    for (int ni = 0; ni < 4; ++ni) {
      const int mrow = m0 + wm * 64 + mi * 16 + lq * 4;
      const int ncol = n0 + wn * 64 + ni * 16 + lr;
      const float bi = bo[ncol];
#pragma unroll
      for (int r = 0; r < 4; ++r)
        out[(size_t)(mrow + r) * 1024 + ncol] = acc[mi][ni][r] + bi;
    }
}

// ---------------------------------------------------------------------------
// MFMA flash attention. Block = (64 q-rows, h, b); 4 waves x 16 q-rows.
// s = qk*0.125*exp(-|i-j|/tau)*(1+ss*0.125); V pre-gated & pre-transposed.
// LDS rows are 128 B -> XOR-swizzle 16B chunk with row&7 (applied on the
// global address at stage time; global_load_lds can't scatter LDS-side).
// ---------------------------------------------------------------------------
__global__ __launch_bounds__(256) void attn_mfma(
    const u16* __restrict__ Qb, const u16* __restrict__ Kb,
    const u16* __restrict__ SPb, const u16* __restrict__ Vt,
    const float* __restrict__ tau, u16* __restrict__ CTXb) {
  __shared__ u16 kbuf[4096], skbuf[4096], vbuf[4096];
  __shared__ u16 pbuf[4][16 * 72];  // pitch 72: conflict-free P round-trip
  const int t = threadIdx.x, l = t & 63, w = t >> 6;
  const int lr = l & 15, lq = l >> 4;
  const int qt = blockIdx.x, h = blockIdx.y, b = blockIdx.z;
  const float inv_tau = 1.0f / tau[h];

  s8v qf[2], sf[2];
  {
    const size_t base = ((size_t)(b * 1024 + qt * 64 + w * 16 + lr)) * 1024 + h * 64 + lq * 8;
    qf[0] = *(const s8v*)(Qb + base);
    qf[1] = *(const s8v*)(Qb + base + 32);
    sf[0] = *(const s8v*)(SPb + base);
    sf[1] = *(const s8v*)(SPb + base + 32);
  }

  const f4v fz = {0.f, 0.f, 0.f, 0.f};
  f4v oacc[4];
  float mrow[4], lrow[4];
#pragma unroll
  for (int i = 0; i < 4; ++i) { oacc[i] = fz; mrow[i] = -INFINITY; lrow[i] = 0.f; }

  const int iq = qt * 64 + w * 16 + lq * 4;
  const int srow = t >> 3;
  const int csw = ((t & 7) ^ (srow & 7)) * 8;  // swizzled chunk (elements)
  u16* myp = pbuf[w];
  const int rx = lr & 7;

  for (int jc = 0; jc < 16; ++jc) {
    const int j0 = jc * 64;
    __syncthreads();
    {
      const size_t kg = ((size_t)(b * 1024 + j0 + srow)) * 1024 + h * 64 + csw;
      gload16(Kb + kg, kbuf + t * 8);
      gload16(Kb + kg + 32 * 1024, kbuf + 2048 + t * 8);
      gload16(SPb + kg, skbuf + t * 8);
      gload16(SPb + kg + 32 * 1024, skbuf + 2048 + t * 8);
      const size_t vg = ((size_t)((b * 16 + h) * 64 + srow)) * 1024 + j0 + csw;
      gload16(Vt + vg, vbuf + t * 8);
      gload16(Vt + vg + 32 * 1024, vbuf + 2048 + t * 8);
    }
    __syncthreads();

    f4v sa[4], ssa[4];
#pragma unroll
    for (int ni = 0; ni < 4; ++ni) { sa[ni] = fz; ssa[ni] = fz; }
#pragma unroll
    for (int ks = 0; ks < 2; ++ks) {
#pragma unroll
      for (int ni = 0; ni < 4; ++ni) {
        const int off = (ni * 16 + lr) * 64 + (((ks * 4 + lq) ^ rx) * 8);
        const s8v kf = *(const s8v*)(kbuf + off);
        sa[ni] = __builtin_amdgcn_mfma_f32_16x16x32_bf16(qf[ks], kf, sa[ni], 0, 0, 0);
        const s8v skf = *(const s8v*)(skbuf + off);
        ssa[ni] = __builtin_amdgcn_mfma_f32_16x16x32_bf16(sf[ks], skf, ssa[ni], 0, 0, 0);
      }
    }

    float p[4][4], alpha[4];
#pragma unroll
    for (int r = 0; r < 4; ++r) {
      float mx = mrow[r];
#pragma unroll
      for (int ni = 0; ni < 4; ++ni) {
        const int j = j0 + ni * 16 + lr;
        const float di = fabsf((float)(iq + r - j));
        const float sc = sa[ni][r] * 0.125f * __expf(-di * inv_tau) *
                         (1.0f + ssa[ni][r] * 0.125f);
        p[ni][r] = sc;
        mx = fmaxf(mx, sc);
      }
#pragma unroll
      for (int o = 1; o < 16; o <<= 1) mx = fmaxf(mx, __shfl_xor(mx, o));
      alpha[r] = __expf(mrow[r] - mx);
      mrow[r] = mx;
      float rs = 0.f;
#pragma unroll
      for (int ni = 0; ni < 4; ++ni) {
        p[ni][r] = __expf(p[ni][r] - mx);
        rs += p[ni][r];
      }
#pragma unroll
      for (int o = 1; o < 16; o <<= 1) rs += __shfl_xor(rs, o);
      lrow[r] = lrow[r] * alpha[r] + rs;
    }
#pragma unroll
    for (int nd = 0; nd < 4; ++nd)
#pragma unroll
      for (int r = 0; r < 4; ++r) oacc[nd][r] *= alpha[r];
#pragma unroll
    for (int ni = 0; ni < 4; ++ni)
#pragma unroll
      for (int r = 0; r < 4; ++r)
        myp[(lq * 4 + r) * 72 + ni * 16 + lr] = f2bf(p[ni][r]);
    // wave-local LDS round-trip (C-layout -> A-layout); compiler orders lgkm
#pragma unroll
    for (int ks = 0; ks < 2; ++ks) {
      const s8v pf = *(const s8v*)(myp + lr * 72 + ks * 32 + lq * 8);
#pragma unroll
      for (int nd = 0; nd < 4; ++nd) {
        const int off = (nd * 16 + lr) * 64 + (((ks * 4 + lq) ^ rx) * 8);
        const s8v vf = *(const s8v*)(vbuf + off);
        oacc[nd] = __builtin_amdgcn_mfma_f32_16x16x32_bf16(pf, vf, oacc[nd], 0, 0, 0);
      }
    }
  }

#pragma unroll
  for (int r = 0; r < 4; ++r) lrow[r] = 1.0f / lrow[r];
#pragma unroll
  for (int nd = 0; nd < 4; ++nd)
#pragma unroll
    for (int r = 0; r < 4; ++r)
      CTXb[((size_t)(b * 1024 + qt * 64 + w * 16 + lq * 4 + r)) * 1024 + h * 64 + nd * 16 + lr]
          = f2bf(oacc[nd][r] * lrow[r]);
}

}  // namespace

extern "C" void kernel_launch(void* const* d_in, const int* in_sizes, int n_in,
                              void* d_out, int out_size, void* d_ws, size_t ws_size,
                              hipStream_t stream) {
  const float* x      = (const float*)d_in[0];
  const float* spikes = (const float*)d_in[1];
  const float* mem    = (const float*)d_in[2];
  const float* Wq     = (const float*)d_in[3];
  const float* bq     = (const float*)d_in[4];
  const float* Wk     = (const float*)d_in[5];
  const float* bk     = (const float*)d_in[6];
  const float* Wv     = (const float*)d_in[7];
  const float* bv     = (const float*)d_in[8];
  const float* Wo     = (const float*)d_in[9];
  const float* bo     = (const float*)d_in[10];
  const float* tau    = (const float*)d_in[11];
  const float* Wg     = (const float*)d_in[12];
  const float* bg     = (const float*)d_in[13];
  float* out = (float*)d_out;

  uint8_t* w8 = (uint8_t*)d_ws;
  u16* xb   = (u16*)(w8);                        // 8 MB  [4096,1024]
  u16* spb  = (u16*)(w8 + (8u << 20));           // 8 MB
  u16* Wqb  = (u16*)(w8 + (16u << 20));          // 2 MB
  u16* Wkb  = (u16*)(w8 + (18u << 20));          // 2 MB
  u16* Wvb  = (u16*)(w8 + (20u << 20));          // 2 MB
  u16* Wob  = (u16*)(w8 + (22u << 20));          // 2 MB
  u16* Wgb  = (u16*)(w8 + (24u << 20));          // 4 MB
  u16* Qb   = (u16*)(w8 + (28u << 20));          // 8 MB
  u16* Kb   = (u16*)(w8 + (36u << 20));          // 8 MB
  u16* Vt   = (u16*)(w8 + (44u << 20));          // 8 MB  [b,h,d,s]
  u16* CTXb = (u16*)(w8 + (52u << 20));          // 8 MB  (total 60 MB)
  u16* memb = Qb;   // Q dead after attention
  u16* gctx = xb;   // x dead after QKV

  // 1) fp32 -> bf16 conversions
  CvtArgs ca;
  ca.j[0] = {x,      xb,  (4096 * 1024) / 4};
  ca.j[1] = {spikes, spb, (4096 * 1024) / 4};
  ca.j[2] = {Wq,     Wqb, (1024 * 1024) / 4};
  ca.j[3] = {Wk,     Wkb, (1024 * 1024) / 4};
  ca.j[4] = {Wv,     Wvb, (1024 * 1024) / 4};
  ca.j[5] = {Wo,     Wob, (1024 * 1024) / 4};
  ca.j[6] = {Wg,     Wgb, (1024 * 2048) / 4};
  cvt_kernel<<<dim3(4096, 7), 256, 0, stream>>>(ca);

  // 2) fused QKV projection (V gated by sigmoid(mem), stored transposed)
  qkv_gemm<<<dim3(24, 32), 256, 0, stream>>>(xb, Wqb, Wkb, Wvb, bq, bk, bv, mem,
                                             Qb, Kb, Vt);
  // 3) flash attention with decay * spike-correlation modifiers
  attn_mfma<<<dim3(16, 16, 4), 256, 0, stream>>>(Qb, Kb, spb, Vt, tau, CTXb);

  // 4) mem -> bf16 into Qb's space (Q now dead)
  CvtArgs cm;
  cm.j[0] = {mem, memb, (4096 * 1024) / 4};
  cvt_kernel<<<dim3(4096, 1), 256, 0, stream>>>(cm);

  // 5) dendritic gate (K=2048 concat via A2 switch)
  gate_gemm<<<dim3(8, 32), 256, 0, stream>>>(CTXb, memb, Wgb, bg, gctx);
  // 6) output projection (fp32 out)
  out_gemm<<<dim3(8, 32), 256, 0, stream>>>(gctx, Wob, bo, out);
}